// Round 14
// baseline (3162.106 us; speedup 1.0000x reference)
//
#include <hip/hip_runtime.h>
#include <hip/hip_fp16.h>
#include <cmath>

#define B_ 32
#define S_ 128
#define T_ 64
#define STEPS_ 63
#define V_ 32000
#define E_ 512
#define H_ 512

typedef __attribute__((ext_vector_type(4))) float f32x4;
typedef __attribute__((ext_vector_type(8))) short bf16x8;
typedef __attribute__((ext_vector_type(2))) _Float16 f16x2;

__device__ inline short f2bf(float x) {
  unsigned u = __builtin_bit_cast(unsigned, x);
  u = (u + 0x7fffu + ((u >> 16) & 1u)) >> 16;
  return (short)u;
}
__device__ inline float bf2f(short h) {
  unsigned u = ((unsigned)(unsigned short)h) << 16;
  return __builtin_bit_cast(float, u);
}
__device__ inline float fdot2(__half2 a, __half2 b, float c) {
#if __has_builtin(__builtin_amdgcn_fdot2)
  return __builtin_amdgcn_fdot2(__builtin_bit_cast(f16x2, a),
                                __builtin_bit_cast(f16x2, b), c, false);
#else
  float2 af = __half22float2(a), bf = __half22float2(b);
  return c + af.x * bf.x + af.y * bf.y;
#endif
}
__device__ inline __half2 bc2(unsigned v) { return __builtin_bit_cast(__half2, v); }
__device__ inline float sigm(float x) { return 1.f / (1.f + expf(-x)); }

// ---- pack GRU weight trio -> k-paired f16 stream for fdot2 ------------------
__global__ __launch_bounds__(256) void k_pack_w3(
    const float* __restrict__ W, int ldw, int col0, __half* __restrict__ W3) {
  int idx = blockIdx.x * 256 + threadIdx.x;   // 98304 = 128 kq * 3 g * 256 up
  int up = idx & 255, g = (idx >> 8) % 3, kq = idx / 768;
  const float* r0 = W + (long)(g * 512 + 2 * up) * ldw + col0 + 4 * kq;
  const float* r1 = r0 + ldw;
  __half h[8];
  h[0] = __float2half(r0[0]); h[1] = __float2half(r0[1]);
  h[2] = __float2half(r1[0]); h[3] = __float2half(r1[1]);
  h[4] = __float2half(r0[2]); h[5] = __float2half(r0[3]);
  h[6] = __float2half(r1[2]); h[7] = __float2half(r1[3]);
  *(uint4*)(W3 + (long)idx * 8) = *(uint4*)h;
}

// ---- MFMA bf16 split GEMM; outmode: 0 f32, 1 f32+tanh, 2 f16; passes 1|3 ----
__global__ __launch_bounds__(256) void k_mfma_gemm(
    const float* __restrict__ A, const float* __restrict__ emb,
    const int* __restrict__ tok, int amode,
    const float* __restrict__ Bmat, long ldb,
    const float* __restrict__ bias,
    void* __restrict__ outp, long sb, long st,
    int M, int N, int K, int outmode, int passes) {
  __shared__ short Ah[128 * 40];
  __shared__ short Al[128 * 40];
  __shared__ short Bh[128 * 40];
  __shared__ short Bl[128 * 40];
  int t = threadIdx.x;
  int n0 = blockIdx.x * 128, m0 = blockIdx.y * 128;
  int ar = t >> 2, ac = (t & 3) * 8;

  const float* arow0;
  const float* arow1;
  {
    int m = m0 + ar;       int mc = m < M ? m : M - 1;
    int m2 = m0 + ar + 64; int mc2 = m2 < M ? m2 : M - 1;
    if (amode == 0) {
      arow0 = A + (long)mc * K;
      arow1 = A + (long)mc2 * K;
    } else {
      int b = mc & 31, q = mc >> 5;
      int tk = (amode == 1) ? tok[b * S_ + q] : tok[b * T_ + q];
      arow0 = emb + (long)tk * K;
      b = mc2 & 31; q = mc2 >> 5;
      tk = (amode == 1) ? tok[b * S_ + q] : tok[b * T_ + q];
      arow1 = emb + (long)tk * K;
    }
  }
  const float* brow0 = Bmat + (long)(n0 + ar) * ldb;
  const float* brow1 = Bmat + (long)(n0 + ar + 64) * ldb;

  int lane = t & 63, wave = t >> 6;
  int wm = (wave >> 1) * 64, wn = (wave & 1) * 64;
  int lr = lane & 15, lk = lane >> 4;
  f32x4 acc[4][4] = {};

  for (int k0 = 0; k0 < K; k0 += 32) {
    auto stage = [&](const float* rowp, short* Dh, short* Dl, int r) {
      float4 x0 = *(const float4*)(rowp + k0 + ac);
      float4 x1 = *(const float4*)(rowp + k0 + ac + 4);
      float xs[8] = {x0.x, x0.y, x0.z, x0.w, x1.x, x1.y, x1.z, x1.w};
      bf16x8 hi, lo;
#pragma unroll
      for (int i = 0; i < 8; ++i) {
        short h = f2bf(xs[i]);
        hi[i] = h;
        lo[i] = f2bf(xs[i] - bf2f(h));
      }
      *(bf16x8*)&Dh[r * 40 + ac] = hi;
      if (passes > 1) *(bf16x8*)&Dl[r * 40 + ac] = lo;
    };
    stage(arow0, Ah, Al, ar);
    stage(arow1, Ah, Al, ar + 64);
    stage(brow0, Bh, Bl, ar);
    stage(brow1, Bh, Bl, ar + 64);
    __syncthreads();

    bf16x8 a_h[4], b_h[4];
#pragma unroll
    for (int i = 0; i < 4; ++i) {
      a_h[i] = *(const bf16x8*)&Ah[(wm + i * 16 + lr) * 40 + lk * 8];
      b_h[i] = *(const bf16x8*)&Bh[(wn + i * 16 + lr) * 40 + lk * 8];
    }
    if (passes > 1) {
      bf16x8 a_l[4], b_l[4];
#pragma unroll
      for (int i = 0; i < 4; ++i) {
        a_l[i] = *(const bf16x8*)&Al[(wm + i * 16 + lr) * 40 + lk * 8];
        b_l[i] = *(const bf16x8*)&Bl[(wn + i * 16 + lr) * 40 + lk * 8];
      }
#pragma unroll
      for (int i = 0; i < 4; ++i)
#pragma unroll
        for (int j = 0; j < 4; ++j) {
          acc[i][j] = __builtin_amdgcn_mfma_f32_16x16x32_bf16(a_l[i], b_h[j], acc[i][j], 0, 0, 0);
          acc[i][j] = __builtin_amdgcn_mfma_f32_16x16x32_bf16(a_h[i], b_l[j], acc[i][j], 0, 0, 0);
        }
    }
#pragma unroll
    for (int i = 0; i < 4; ++i)
#pragma unroll
      for (int j = 0; j < 4; ++j)
        acc[i][j] = __builtin_amdgcn_mfma_f32_16x16x32_bf16(a_h[i], b_h[j], acc[i][j], 0, 0, 0);
    __syncthreads();
  }

#pragma unroll
  for (int i = 0; i < 4; ++i) {
#pragma unroll
    for (int r = 0; r < 4; ++r) {
      int m = m0 + wm + i * 16 + lk * 4 + r;
      if (m >= M) continue;
      long base = (long)(m & 31) * sb + (long)(m >> 5) * st;
#pragma unroll
      for (int j = 0; j < 4; ++j) {
        int n = n0 + wn + j * 16 + lr;
        float v = acc[i][j][r] + bias[n];
        if (outmode == 2) ((__half*)outp)[base + n] = __float2half(v);
        else ((float*)outp)[base + n] = (outmode == 1) ? tanhf(v) : v;
      }
    }
  }
}

// ---- encoder: 64 blocks (pair b, b+32 on same XCD), u-half split -----------
// Per block: 768 streamer threads pull HALF the weights (0.75 MB/step);
// h-halves exchanged via agent-scope atomics + flag handshake.
__global__ __launch_bounds__(1024) void k_enc_all(
    const float* __restrict__ gi_all,      // [S*B][1536], row = s*32+b (bih folded)
    const __half* __restrict__ W3,         // packed Whh_e
    const float* __restrict__ bhh, const int* __restrict__ lens,
    float* __restrict__ h_out,
    __half* __restrict__ EO16,             // [32][128][512] (pre-zeroed)
    float* __restrict__ EO32,              // [4096][512]    (pre-zeroed)
    unsigned* __restrict__ hbuf,           // [32][2][128] u32 (=256 f16 per half)
    int* __restrict__ flags) {             // [32][2] (pre-zeroed)
  __shared__ __align__(8) __half2 hs16[256];
  __shared__ float pGh[768];
  __shared__ float gis[768];
  int blk = blockIdx.x, t = threadIdx.x;
  int b = blk & 31, half = blk >> 5;       // pair (b, b+32) -> same XCD (%8)
  int len = lens[b];
  int u0g = half * 256;
  int* flagOwn = flags + b * 2 + half;
  int* flagP   = flags + b * 2 + (1 - half);
  unsigned* hbOwn = hbuf + (b * 2 + half) * 128;
  unsigned* hbP   = hbuf + (b * 2 + (1 - half)) * 128;
  float br0 = 0, br1 = 0, bz0 = 0, bz1 = 0, bn0 = 0, bn1 = 0;
  float hold0 = 0.f, hold1 = 0.f;
  if (t < 128) {
    int u = u0g + 2 * t;
    br0 = bhh[u]; br1 = bhh[u + 1];
    bz0 = bhh[512 + u]; bz1 = bhh[512 + u + 1];
    bn0 = bhh[1024 + u]; bn1 = bhh[1024 + u + 1];
  }
  if (t < 256) hs16[t] = __float22half2_rn(make_float2(0.f, 0.f));
  __syncthreads();

  // streamer mapping: c in [0,768): g = c>>8, rem = c&255,
  // up_loc = rem>>1 (0..127), kh2 = rem&1 -> kq in [kh2*64, kh2*64+64)
  int c = t - 256;
  int g = c >> 8, rem = c & 255;
  int up_loc = rem >> 1, kh2 = rem & 1;
  int up = half * 128 + up_loc;
  const __half* wb = W3 + (long)(kh2 * 64) * 6144 + (long)(g * 256 + up) * 8;

  for (int s = 0; s < S_; ++s) {
    if (s == len) break;
    if (s > 0) {
      if (t == 0) {
        while (__hip_atomic_load(flagP, __ATOMIC_ACQUIRE, __HIP_MEMORY_SCOPE_AGENT) < s)
          __builtin_amdgcn_s_sleep(1);
      }
      __syncthreads();
      if (t < 128) {
        unsigned v = __hip_atomic_load(hbP + t, __ATOMIC_RELAXED, __HIP_MEMORY_SCOPE_AGENT);
        hs16[(1 - half) * 128 + t] = bc2(v);
      }
    }
    __syncthreads();   // hs16 = full h(s)
    if (t >= 256) {
      float a0 = 0.f, a1 = 0.f;
#pragma unroll 8
      for (int kq2 = 0; kq2 < 64; ++kq2) {
        uint4 w8 = *(const uint4*)(wb + (long)kq2 * 6144);
        int kq = kh2 * 64 + kq2;
        __half2 x01 = hs16[2 * kq], x23 = hs16[2 * kq + 1];
        a0 = fdot2(x01, bc2(w8.x), a0); a1 = fdot2(x01, bc2(w8.y), a1);
        a0 = fdot2(x23, bc2(w8.z), a0); a1 = fdot2(x23, bc2(w8.w), a1);
      }
      a0 += __shfl_xor(a0, 1, 64);
      a1 += __shfl_xor(a1, 1, 64);
      if (kh2 == 0) {
        pGh[g * 256 + 2 * up_loc] = a0;
        pGh[g * 256 + 2 * up_loc + 1] = a1;
      }
    } else if (t >= 128) {
      const float* gi = gi_all + ((long)s * 32 + b) * 1536;
      int i = t - 128;
      gis[2 * i] = gi[u0g + 2 * i];
      gis[2 * i + 1] = gi[u0g + 2 * i + 1];
      gis[256 + 2 * i] = gi[512 + u0g + 2 * i];
      gis[256 + 2 * i + 1] = gi[512 + u0g + 2 * i + 1];
      gis[512 + 2 * i] = gi[1024 + u0g + 2 * i];
      gis[512 + 2 * i + 1] = gi[1024 + u0g + 2 * i + 1];
    }
    __syncthreads();
    if (t < 128) {
      int l0 = 2 * t;
      float r0 = sigm(gis[l0] + pGh[l0] + br0);
      float r1 = sigm(gis[l0 + 1] + pGh[l0 + 1] + br1);
      float z0 = sigm(gis[256 + l0] + pGh[256 + l0] + bz0);
      float z1 = sigm(gis[256 + l0 + 1] + pGh[256 + l0 + 1] + bz1);
      float n0 = tanhf(gis[512 + l0] + r0 * (pGh[512 + l0] + bn0));
      float n1 = tanhf(gis[512 + l0 + 1] + r1 * (pGh[512 + l0 + 1] + bn1));
      hold0 = (1.f - z0) * n0 + z0 * hold0;
      hold1 = (1.f - z1) * n1 + z1 * hold1;
      __half2 h2 = __float22half2_rn(make_float2(hold0, hold1));
      hs16[half * 128 + t] = h2;
      long row = (long)b * 128 + s;
      *(__half2*)(EO16 + row * 512 + u0g + l0) = h2;
      *(float2*)(EO32 + row * 512 + u0g + l0) = make_float2(hold0, hold1);
      __hip_atomic_store(hbOwn + t, __builtin_bit_cast(unsigned, h2),
                         __ATOMIC_RELAXED, __HIP_MEMORY_SCOPE_AGENT);
    }
    __syncthreads();
    if (t == 0) {
      __threadfence();
      __hip_atomic_store(flagOwn, s + 1, __ATOMIC_RELEASE, __HIP_MEMORY_SCOPE_AGENT);
    }
  }
  if (t < 128) *(float2*)(h_out + b * 512 + u0g + 2 * t) = make_float2(hold0, hold1);
}

// ---- decoder: 32 blocks x 1024 thr; 4-region overlapped step (R13-proven) ---
__global__ __launch_bounds__(1024) void k_dec_all(
    const float* __restrict__ gie,         // [STEPS*B][1536], row = t*32+b
    const __half* __restrict__ EO16g,      // [32][128][512]
    const __half* __restrict__ W3,         // packed Whh_d
    const __half* __restrict__ GV,         // [4096][1536] f16, row = b*128+s
    const float* __restrict__ bhh, const int* __restrict__ lens,
    const float* __restrict__ h_init,
    float* __restrict__ hctx,              // [2016+][1024]: [0:512]=hn [512:1024]=ctx
    float* __restrict__ attns) {
  __shared__ __align__(16) __half2 EOs[32768];   // 128 KB linear [s][c]
  __shared__ __align__(8) __half2 hs16[256];
  __shared__ float pGh[1536];
  __shared__ float pGc[1536];
  __shared__ float gis[1536];
  __shared__ float sc[128];
  int b = blockIdx.x, t = threadIdx.x;
  int lane = t & 63, wave = t >> 6;
  int len = lens[b];
  float br0 = 0, br1 = 0, bz0 = 0, bz1 = 0, bn0 = 0, bn1 = 0, hold0 = 0, hold1 = 0;
  if (t < 256) {
    br0 = bhh[2 * t]; br1 = bhh[2 * t + 1];
    bz0 = bhh[512 + 2 * t]; bz1 = bhh[512 + 2 * t + 1];
    bn0 = bhh[1024 + 2 * t]; bn1 = bhh[1024 + 2 * t + 1];
    float2 h2 = *(const float2*)(h_init + b * 512 + 2 * t);
    hold0 = h2.x; hold1 = h2.y;
    hs16[t] = __float22half2_rn(h2);
  }
  {
    const uint4* src = (const uint4*)(EO16g + (long)b * 128 * 512);
    uint4* dst = (uint4*)EOs;
    for (int i = t; i < 8192; i += 1024) dst[i] = src[i];
  }
  __syncthreads();
  const __half2* GVb = (const __half2*)GV + (long)b * 128 * 768;

  for (int step = 0; step < STEPS_; ++step) {
    long row = (long)step * 32 + b;
    // ---- R1: Whh GEMV (t<768) || raw scores (t>=768) ----
    if (t < 768) {
      int g = t >> 8, up = t & 255;
      const __half* wb = W3 + (long)(g * 256 + up) * 8;
      float a0 = 0.f, a1 = 0.f;
#pragma unroll 8
      for (int kq = 0; kq < 128; ++kq) {
        uint4 w8 = *(const uint4*)(wb + (long)kq * 6144);
        __half2 x01 = hs16[2 * kq], x23 = hs16[2 * kq + 1];
        a0 = fdot2(x01, bc2(w8.x), a0); a1 = fdot2(x01, bc2(w8.y), a1);
        a0 = fdot2(x23, bc2(w8.z), a0); a1 = fdot2(x23, bc2(w8.w), a1);
      }
      pGh[g * 512 + 2 * up] = a0;
      pGh[g * 512 + 2 * up + 1] = a1;
    } else {
      int w = wave - 12;                     // 0..3, each 32 s-rows
      uint4 hv = ((const uint4*)hs16)[lane];
      __half2 h0 = bc2(hv.x), h1 = bc2(hv.y), h2 = bc2(hv.z), h3 = bc2(hv.w);
#pragma unroll 4
      for (int si = 0; si < 32; ++si) {
        int s = w * 32 + si;
        uint4 ev = ((const uint4*)&EOs[s * 256])[lane];
        float p = 0.f;
        p = fdot2(bc2(ev.x), h0, p);
        p = fdot2(bc2(ev.y), h1, p);
        p = fdot2(bc2(ev.z), h2, p);
        p = fdot2(bc2(ev.w), h3, p);
#pragma unroll
        for (int off = 32; off > 0; off >>= 1) p += __shfl_down(p, off, 64);
        if (lane == 0) sc[s] = p;
      }
    }
    __syncthreads();
    // ---- R2: softmax (wave 0) || gis prefetch (t in [64,448)) ----
    if (t < 64) {
      float p0 = sc[lane], p1 = sc[64 + lane];
      bool v0 = lane < len, v1 = 64 + lane < len;
      float m = fmaxf(v0 ? p0 : -INFINITY, v1 ? p1 : -INFINITY);
#pragma unroll
      for (int off = 32; off > 0; off >>= 1) m = fmaxf(m, __shfl_xor(m, off, 64));
      float e0 = v0 ? expf(p0 - m) : 0.f;
      float e1 = v1 ? expf(p1 - m) : 0.f;
      float S = e0 + e1;
#pragma unroll
      for (int off = 32; off > 0; off >>= 1) S += __shfl_xor(S, off, 64);
      float aw0 = e0 / S, aw1 = e1 / S;
      sc[lane] = aw0;
      sc[64 + lane] = aw1;
      float* ap = attns + ((long)b * STEPS_ + step) * 128;
      ap[lane] = aw0;
      ap[64 + lane] = aw1;
    } else if (t < 448) {
      int i0 = (t - 64) * 4;
      *(float4*)(gis + i0) = *(const float4*)(gie + row * 1536 + i0);
    }
    __syncthreads();
    // ---- R3: GV weighted sum (t<768) || ctx from EOs (t>=768) ----
    if (t < 768) {
      float ax = 0.f, ay = 0.f;
      for (int s = 0; s < 128; ++s) {
        if (s == len) break;
        float aw = sc[s];
        float2 g2 = __half22float2(GVb[(long)s * 768 + t]);
        ax += aw * g2.x;
        ay += aw * g2.y;
      }
      pGc[2 * t] = ax;
      pGc[2 * t + 1] = ay;
    } else {
      int c = t - 768;
      float ax = 0.f, ay = 0.f;
      for (int s = 0; s < 128; ++s) {
        if (s == len) break;
        float aw = sc[s];
        float2 e2 = __half22float2(EOs[s * 256 + c]);
        ax += aw * e2.x;
        ay += aw * e2.y;
      }
      *(float2*)(hctx + row * 1024 + 512 + 2 * c) = make_float2(ax, ay);
    }
    __syncthreads();
    // ---- R4: cell (t<256) ----
    if (t < 256) {
      int u0 = 2 * t;
      float r0 = sigm(gis[u0] + pGc[u0] + pGh[u0] + br0);
      float r1 = sigm(gis[u0 + 1] + pGc[u0 + 1] + pGh[u0 + 1] + br1);
      float z0 = sigm(gis[512 + u0] + pGc[512 + u0] + pGh[512 + u0] + bz0);
      float z1 = sigm(gis[512 + u0 + 1] + pGc[512 + u0 + 1] + pGh[512 + u0 + 1] + bz1);
      float n0 = tanhf(gis[1024 + u0] + pGc[1024 + u0] + r0 * (pGh[1024 + u0] + bn0));
      float n1 = tanhf(gis[1024 + u0 + 1] + pGc[1024 + u0 + 1] + r1 * (pGh[1024 + u0 + 1] + bn1));
      hold0 = (1.f - z0) * n0 + z0 * hold0;
      hold1 = (1.f - z1) * n1 + z1 * hold1;
      hs16[t] = __float22half2_rn(make_float2(hold0, hold1));
      *(float2*)(hctx + row * 1024 + u0) = make_float2(hold0, hold1);
    }
    __syncthreads();
  }
}

extern "C" void kernel_launch(void* const* d_in, const int* in_sizes, int n_in,
                              void* d_out, int out_size, void* d_ws, size_t ws_size,
                              hipStream_t stream) {
  (void)in_sizes; (void)n_in; (void)out_size; (void)ws_size;
  const int*   src   = (const int*)d_in[0];
  const int*   lens  = (const int*)d_in[1];
  const int*   tgt   = (const int*)d_in[2];
  const float* emb_e = (const float*)d_in[3];
  const float* Wih_e = (const float*)d_in[4];
  const float* Whh_e = (const float*)d_in[5];
  const float* bih_e = (const float*)d_in[6];
  const float* bhh_e = (const float*)d_in[7];
  const float* emb_d = (const float*)d_in[8];
  const float* Wih_d = (const float*)d_in[9];
  const float* Whh_d = (const float*)d_in[10];
  const float* bih_d = (const float*)d_in[11];
  const float* bhh_d = (const float*)d_in[12];
  const float* Wc    = (const float*)d_in[13];
  const float* bc    = (const float*)d_in[14];
  const float* Wo    = (const float*)d_in[15];
  const float* bo    = (const float*)d_in[16];

  float* logits = (float*)d_out;
  float* attns  = (float*)d_out + (long)B_ * STEPS_ * V_;

  float* w = (float*)d_ws;
  __half* W3e  = (__half*)w;                    // 786432 halves (1.5MB)
  __half* W3d  = (__half*)(w + 393216);         // 1.5MB
  float*  zb   = w + 786432;                    // 1536 zeros (GV bias)
  float*  GIe  = w + 788480;                    // 4096 x 1536 f32
  float*  GId  = GIe + 6291456;                 // 2048 x 1536 f32
  __half* EO16 = (__half*)(GId + 3145728);      // 4MB
  float*  EO32 = GId + 3145728 + 1048576;       // 8MB
  float*  h0   = EO32 + 2097152;                // 32 x 512
  unsigned* hbuf  = (unsigned*)(h0 + 16384);    // 32*2*128 u32 = 32KB
  int*      flags = (int*)(hbuf + 8192);        // 64 ints
  // overlays inside GIe (dead after encoder):
  __half* GV    = (__half*)GIe;                 // 4096 x 1536 f16
  float*  hctx  = GIe + 3145728;                // 2048 x 1024 f32
  float*  ccall = GIe + 5242880;                // 2016 x 512 f32

  hipMemsetAsync(EO16, 0, 2097152 * sizeof(__half), stream);
  hipMemsetAsync(EO32, 0, 2097152 * sizeof(float), stream);
  hipMemsetAsync(zb, 0, 1536 * sizeof(float), stream);
  hipMemsetAsync(flags, 0, 64 * sizeof(int), stream);

  k_pack_w3<<<384, 256, 0, stream>>>(Whh_e, 512, 0, W3e);
  k_pack_w3<<<384, 256, 0, stream>>>(Whh_d, 512, 0, W3d);

  // GIe = emb_enc[src] @ Wih_e^T + bih_e   (single-pass bf16)
  k_mfma_gemm<<<dim3(1536 / 128, 4096 / 128), 256, 0, stream>>>(
      nullptr, emb_e, src, 1, Wih_e, 512, bih_e, GIe, 1536L, 32L * 1536L,
      4096, 1536, 512, 0, 1);
  // GId = emb_dec[tgt] @ Wih_d[:, :512]^T + bih_d   (single-pass bf16)
  k_mfma_gemm<<<dim3(1536 / 128, (2016 + 127) / 128), 256, 0, stream>>>(
      nullptr, emb_d, tgt, 2, Wih_d, 1024, bih_d, GId, 1536L, 32L * 1536L,
      2016, 1536, 512, 0, 1);

  k_enc_all<<<64, 1024, 0, stream>>>(GIe, W3e, bhh_e, lens, h0, EO16, EO32,
                                     hbuf, flags);

  // GV = EO32 @ Wih_d[:,512:1024]^T (f16 out, zero bias, single-pass)
  k_mfma_gemm<<<dim3(1536 / 128, 4096 / 128), 256, 0, stream>>>(
      EO32, nullptr, nullptr, 0, Wih_d + 512, 1024, zb, GV, 1536L, 49152L,
      4096, 1536, 512, 2, 1);

  k_dec_all<<<32, 1024, 0, stream>>>(GId, EO16, W3d, GV, bhh_d, lens, h0,
                                     hctx, attns);

  // cc = tanh([hn|ctx] @ Wc^T + bc) (single-pass)
  k_mfma_gemm<<<dim3(512 / 128, (2016 + 127) / 128), 256, 0, stream>>>(
      hctx, nullptr, nullptr, 0, Wc, 1024, bc, ccall, 512L, 16384L,
      2016, 512, 1024, 1, 1);

  // logits = ccall @ Wo^T + bo (single-pass)
  k_mfma_gemm<<<dim3(V_ / 128, (2016 + 127) / 128), 256, 0, stream>>>(
      ccall, nullptr, nullptr, 0, Wo, 512, bo, logits,
      (long)STEPS_ * V_, (long)V_, 2016, 32000, 512, 0, 1);
}